// Round 4
// baseline (102.752 us; speedup 1.0000x reference)
//
#include <hip/hip_runtime.h>
#include <math.h>

// Tropical (max-plus) matmul: out[b,o] = max_k ( x[b,k] + W[o,k] )
// x: (2048,512) f32, W: (512,512) f32, out: (2048,512) f32.
//
// R6 post-mortem: timed e2e identical for unroll-16 vs unroll-4 (93.47 vs
// 93.43) -> I$ capacity not primary. Accounting across all rounds fits
// timed = ~40us ws-re-poison fill (268MB rocclr fills observed) + main
// ~46us + reduce. main's 46us vs 7-8us VALU/LDS floors = latency exposure
// at 2 waves/SIMD; R5's extra *small* blocks were never co-scheduled.
// R7: force residency via block shape: 512-thread blocks, BM=256 BN=128,
// SPLITK=16, KT=1 -> 512 blocks = 2 blocks/CU = 4 waves/SIMD guaranteed.
// Per-thread 8x8 tile and LDS ratios unchanged. Swizzle dropped (proven
// no-op: B reads are contiguous/2-way-free; the 2^20 conflict counter is
// benign staging-write bank-rounds, invariant across variants).

typedef float f2v __attribute__((ext_vector_type(2)));
typedef float f4v __attribute__((ext_vector_type(4)));

#define B_ROWS 2048
#define K_DIM  512
#define O_DIM  512
#define BM 256
#define BN 128
#define BK 32
#define SPLITK 16
#define KRANGE (K_DIM / SPLITK)   // 32 = BK -> single k-tile per block

__device__ __forceinline__ void atomic_max_f32(float* p, float v) {
    unsigned int* up = (unsigned int*)p;
    unsigned int cur = *(volatile unsigned int*)up;
    while (__uint_as_float(cur) < v) {
        unsigned int assumed = cur;
        cur = atomicCAS(up, assumed, __float_as_uint(v));
        if (cur == assumed) break;
    }
}

template <bool USE_WS>
__global__ __launch_bounds__(512, 2) void tropical_main(
    const float* __restrict__ x, const float* __restrict__ W,
    float* __restrict__ dst)  // USE_WS: ws partials base; else d_out
{
    // k-pair-major LDS: [kp][row] = { v[2kp][row], v[2kp+1][row] }.
    __shared__ __align__(16) f2v xs2[BK / 2][BM];   // 32 KB
    __shared__ __align__(16) f2v ws2[BK / 2][BN];   // 16 KB

    const int t  = threadIdx.x;
    const int bx = blockIdx.x;
    const int bn = (bx & 3) * BN;          // 4 N-tiles
    const int bm = ((bx >> 2) & 7) * BM;   // 8 M-tiles
    const int ks = bx >> 5;                // 16 K-splits
    const int k0 = ks * KRANGE;

    // ---- staging (single k-tile, no loop) ----
    // A: 256 rows x 2 halves = 512 slots -> all threads.
    const int rowA = t & 255;
    const int khA  = t >> 8;               // 0/1 -> k-offset 16*khA
    // B: 128 rows x 2 halves = 256 slots -> threads 0..255 (waves 0-3).
    const int rowB = t & 127;
    const int khB  = (t >> 7) & 1;
    const bool doB = t < 256;

    const float* xb = x + (size_t)(bm + rowA) * K_DIM + k0 + 16 * khA;
    const float* wb = W + (size_t)(bn + rowB) * K_DIM + k0 + 16 * khB;

    float4 pa[4], pb[4];
#pragma unroll
    for (int q = 0; q < 4; ++q) pa[q] = *(const float4*)(xb + 4 * q);
    if (doB) {
#pragma unroll
        for (int q = 0; q < 4; ++q) pb[q] = *(const float4*)(wb + 4 * q);
    }

#pragma unroll
    for (int q = 0; q < 4; ++q) {
        const int kp = 8 * khA + 2 * q;
        xs2[kp][rowA]     = (f2v){pa[q].x, pa[q].y};
        xs2[kp + 1][rowA] = (f2v){pa[q].z, pa[q].w};
    }
    if (doB) {
#pragma unroll
        for (int q = 0; q < 4; ++q) {
            const int kp = 8 * khB + 2 * q;
            ws2[kp][rowB]     = (f2v){pb[q].x, pb[q].y};
            ws2[kp + 1][rowB] = (f2v){pb[q].z, pb[q].w};
        }
    }
    __syncthreads();

    // ---- compute: 16x32 thread grid, 8x8 register tile as (4+4)x(4+4) ----
    const int tx = t & 15;
    const int ty = t >> 4;                 // 0..31
    const int c0 = tx * 4, c1 = 64 + tx * 4;
    const int r0 = ty * 4, r1 = 128 + ty * 4;

    float acc[2][4][2][4];  // [ri][i][ci][j]
#pragma unroll
    for (int ri = 0; ri < 2; ++ri)
#pragma unroll
        for (int i = 0; i < 4; ++i)
#pragma unroll
            for (int ci = 0; ci < 2; ++ci)
#pragma unroll
                for (int j = 0; j < 4; ++j) acc[ri][i][ci][j] = -INFINITY;

    // 16 k-pairs: 8 b128 reads + 64 x (v_pk_add_f32 + v_max3_f32) each.
#pragma unroll 4
    for (int kp = 0; kp < BK / 2; ++kp) {
        f4v A[2][2], B[2][2];
        A[0][0] = *(const f4v*)&xs2[kp][r0];
        A[0][1] = *(const f4v*)&xs2[kp][r0 + 2];
        A[1][0] = *(const f4v*)&xs2[kp][r1];
        A[1][1] = *(const f4v*)&xs2[kp][r1 + 2];
        B[0][0] = *(const f4v*)&ws2[kp][c0];
        B[0][1] = *(const f4v*)&ws2[kp][c0 + 2];
        B[1][0] = *(const f4v*)&ws2[kp][c1];
        B[1][1] = *(const f4v*)&ws2[kp][c1 + 2];

        f2v a2[2][4], b2[2][4];
#pragma unroll
        for (int h = 0; h < 2; ++h) {
            a2[h][0] = A[h][0].xy; a2[h][1] = A[h][0].zw;
            a2[h][2] = A[h][1].xy; a2[h][3] = A[h][1].zw;
            b2[h][0] = B[h][0].xy; b2[h][1] = B[h][0].zw;
            b2[h][2] = B[h][1].xy; b2[h][3] = B[h][1].zw;
        }
#pragma unroll
        for (int ri = 0; ri < 2; ++ri)
#pragma unroll
            for (int i = 0; i < 4; ++i)
#pragma unroll
                for (int ci = 0; ci < 2; ++ci)
#pragma unroll
                    for (int j = 0; j < 4; ++j) {
                        f2v s = a2[ri][i] + b2[ci][j];      // v_pk_add_f32
                        acc[ri][i][ci][j] =
                            fmaxf(acc[ri][i][ci][j],
                                  fmaxf(s.x, s.y));         // v_max3_f32
                    }
    }

    // ---- epilogue ----
    if (USE_WS) {
        float* outp = dst + (size_t)ks * (B_ROWS * O_DIM);
#pragma unroll
        for (int ri = 0; ri < 2; ++ri) {
            const int rb = bm + (ri ? r1 : r0);
#pragma unroll
            for (int i = 0; i < 4; ++i) {
                float4 v0, v1;
                v0.x = acc[ri][i][0][0]; v0.y = acc[ri][i][0][1];
                v0.z = acc[ri][i][0][2]; v0.w = acc[ri][i][0][3];
                v1.x = acc[ri][i][1][0]; v1.y = acc[ri][i][1][1];
                v1.z = acc[ri][i][1][2]; v1.w = acc[ri][i][1][3];
                *(float4*)(outp + (size_t)(rb + i) * O_DIM + bn + c0) = v0;
                *(float4*)(outp + (size_t)(rb + i) * O_DIM + bn + c1) = v1;
            }
        }
    } else {
#pragma unroll
        for (int ri = 0; ri < 2; ++ri) {
            const int rb = bm + (ri ? r1 : r0);
#pragma unroll
            for (int i = 0; i < 4; ++i)
#pragma unroll
                for (int ci = 0; ci < 2; ++ci)
#pragma unroll
                    for (int j = 0; j < 4; ++j) {
                        const int gc = bn + (ci ? c1 : c0) + j;
                        atomic_max_f32(dst + (size_t)(rb + i) * O_DIM + gc,
                                       acc[ri][i][ci][j]);
                    }
        }
    }
}

__global__ __launch_bounds__(256) void tropical_reduce(
    const float4* __restrict__ ws, float4* __restrict__ out)
{
    const int i = blockIdx.x * 256 + threadIdx.x;   // 0..262143
    const int Q = B_ROWS * O_DIM / 4;               // 262144
    float4 r = ws[i];
#pragma unroll
    for (int p = 1; p < SPLITK; ++p) {
        float4 v = ws[i + p * Q];
        r.x = fmaxf(r.x, v.x);
        r.y = fmaxf(r.y, v.y);
        r.z = fmaxf(r.z, v.z);
        r.w = fmaxf(r.w, v.w);
    }
    out[i] = r;
}

__global__ __launch_bounds__(256) void tropical_fill(float4* __restrict__ out)
{
    const int i = blockIdx.x * 256 + threadIdx.x;
    out[i] = make_float4(-INFINITY, -INFINITY, -INFINITY, -INFINITY);
}

extern "C" void kernel_launch(void* const* d_in, const int* in_sizes, int n_in,
                              void* d_out, int out_size, void* d_ws, size_t ws_size,
                              hipStream_t stream) {
    const float* x = (const float*)d_in[0];   // (2048, 512)
    const float* W = (const float*)d_in[1];   // (512, 512)
    float* out = (float*)d_out;               // (2048, 512)

    const size_t partial_bytes =
        (size_t)SPLITK * B_ROWS * O_DIM * sizeof(float);     // 64 MB
    const int nblocks = 8 * 4 * SPLITK;                      // 512
    const int nred = (B_ROWS * O_DIM / 4) / 256;             // 1024

    if (ws_size >= partial_bytes) {
        tropical_main<true><<<nblocks, 512, 0, stream>>>(x, W, (float*)d_ws);
        tropical_reduce<<<nred, 256, 0, stream>>>(
            (const float4*)d_ws, (float4*)out);
    } else {
        tropical_fill<<<nred, 256, 0, stream>>>((float4*)out);
        tropical_main<false><<<nblocks, 512, 0, stream>>>(x, W, out);
    }
}